// Round 1
// baseline (817.221 us; speedup 1.0000x reference)
//
#include <hip/hip_runtime.h>
#include <hip/hip_bf16.h>
#include <stdint.h>

// FoodRiskGNN: 2-layer GraphSAGE (mean aggr), N=100000, E=1600000, 64->128->64.
// Pipeline per launch (all on `stream`):
//   memset deg -> hist -> scan (CSR rowptr) -> fill (CSR cols) -> transpose W
//   -> agg1 = mean-gather(x)          [bf16]
//   -> h    = relu(agg1@Wl1 + x@Wr1 + b1)   [bf16]
//   -> y2   = h@Wl2                   [bf16]   (linearity: aggregate AFTER transform)
//   -> agg2 = mean-gather(y2)         [bf16, reuses agg1 buffer]
//   -> out  = sigmoid(agg2 + h@Wr2 + b2)     [f32]

__device__ __forceinline__ float ldf(const float* p) { return *p; }
__device__ __forceinline__ float ldf(const __hip_bfloat16* p) { return __bfloat162float(*p); }

__device__ __forceinline__ void unpack8(uint4 v, float* a) {
  unsigned int u[4] = {v.x, v.y, v.z, v.w};
#pragma unroll
  for (int i = 0; i < 4; ++i) {
    a[2 * i]     = __uint_as_float(u[i] << 16);
    a[2 * i + 1] = __uint_as_float(u[i] & 0xffff0000u);
  }
}

__global__ void k_hist(const int* __restrict__ dst, int* __restrict__ deg, int E) {
  int i = blockIdx.x * blockDim.x + threadIdx.x;
  if (i < E) atomicAdd(&deg[dst[i]], 1);
}

__global__ __launch_bounds__(1024) void k_scan(const int* __restrict__ deg,
                                               int* __restrict__ rowptr,
                                               int* __restrict__ cursor, int n) {
  __shared__ int wsum[17];
  __shared__ int running;
  const int tid = threadIdx.x, lane = tid & 63, w = tid >> 6;
  if (tid == 0) running = 0;
  __syncthreads();
  for (int base = 0; base < n; base += 1024) {
    int i = base + tid;
    int v = (i < n) ? deg[i] : 0;
    int s = v;  // inclusive wave scan
#pragma unroll
    for (int off = 1; off < 64; off <<= 1) {
      int t = __shfl_up(s, off);
      if (lane >= off) s += t;
    }
    if (lane == 63) wsum[w] = s;
    __syncthreads();
    if (tid == 0) {
      int acc = 0;
#pragma unroll
      for (int q = 0; q < 16; ++q) { int t = wsum[q]; wsum[q] = acc; acc += t; }
      wsum[16] = acc;
    }
    __syncthreads();
    int excl = running + wsum[w] + (s - v);
    if (i < n) { rowptr[i] = excl; cursor[i] = excl; }
    __syncthreads();
    if (tid == 0) running += wsum[16];
    __syncthreads();
  }
  if (threadIdx.x == 0) rowptr[n] = running;
}

__global__ void k_fill(const int* __restrict__ src, const int* __restrict__ dst,
                       int* __restrict__ cursor, int* __restrict__ csr, int E) {
  int i = blockIdx.x * blockDim.x + threadIdx.x;
  if (i < E) {
    int d = dst[i];
    int p = atomicAdd(&cursor[d], 1);
    csr[p] = src[i];
  }
}

__global__ void k_transpose(const float* __restrict__ A, const float* __restrict__ B,
                            const float* __restrict__ C, const float* __restrict__ D,
                            float* __restrict__ AT, float* __restrict__ BT,
                            float* __restrict__ CT, float* __restrict__ DT) {
  int i = blockIdx.x * blockDim.x + threadIdx.x;
  if (i < 64 * 128) {
    int k = i >> 7, j = i & 127;  // A,B: [64][128]
    AT[j * 64 + k] = A[i];
    BT[j * 64 + k] = B[i];
    int k2 = i >> 6, j2 = i & 63; // C,D: [128][64]
    CT[j2 * 128 + k2] = C[i];
    DT[j2 * 128 + k2] = D[i];
  }
}

// mean-gather over CSR: one wave per node, lane = channel (F=64).
template <typename T>
__global__ void k_agg(const T* __restrict__ feat, const int* __restrict__ rowptr,
                      const int* __restrict__ csr, __hip_bfloat16* __restrict__ out, int n) {
  const int lane = threadIdx.x & 63;
  const int wid =
      __builtin_amdgcn_readfirstlane((int)(blockIdx.x * (blockDim.x >> 6) + (threadIdx.x >> 6)));
  const int nw = (gridDim.x * blockDim.x) >> 6;
  for (int node = wid; node < n; node += nw) {
    int beg = rowptr[node], end = rowptr[node + 1];
    float acc = 0.f;
    for (int e = beg; e < end; ++e) {
      int s = csr[e];  // wave-uniform -> s_load
      acc += ldf(feat + (size_t)s * 64 + lane);
    }
    if (end > beg) acc *= (1.0f / (float)(end - beg));
    out[(size_t)node * 64 + lane] = __float2bfloat16(acc);
  }
}

// h = relu(agg1@Wl1 + x@Wr1 + b1). lane = node (64-node tile/block), wave owns 32 of 128 outputs.
__global__ __launch_bounds__(256) void k_gemm1(const float* __restrict__ x,
                                               const __hip_bfloat16* __restrict__ agg1,
                                               const float* __restrict__ WlT,
                                               const float* __restrict__ WrT,
                                               const float* __restrict__ b1,
                                               __hip_bfloat16* __restrict__ h, int n) {
  __shared__ __align__(16) __hip_bfloat16 sO[64][130];
  const int lane = threadIdx.x & 63;
  const int w = __builtin_amdgcn_readfirstlane((int)(threadIdx.x >> 6));
  const int n0 = blockIdx.x * 64;
  const int node = (n0 + lane < n) ? (n0 + lane) : (n - 1);

  float a[64], xr[64];
  {
    const uint4* pa = (const uint4*)(agg1 + (size_t)node * 64);
#pragma unroll
    for (int c = 0; c < 8; ++c) unpack8(pa[c], &a[c * 8]);
    const float4* px = (const float4*)(x + (size_t)node * 64);
#pragma unroll
    for (int c = 0; c < 16; ++c) {
      float4 v = px[c];
      xr[4 * c] = v.x; xr[4 * c + 1] = v.y; xr[4 * c + 2] = v.z; xr[4 * c + 3] = v.w;
    }
  }
  const int j0 = w * 32;
  for (int jj = 0; jj < 32; jj += 2) {
    const int j = j0 + jj;                 // wave-uniform -> weight s_loads
    const float* wl0 = WlT + j * 64;
    const float* wr0 = WrT + j * 64;
    const float* wl1 = WlT + (j + 1) * 64;
    const float* wr1 = WrT + (j + 1) * 64;
    float acc0 = b1[j], acc1 = b1[j + 1];
#pragma unroll
    for (int k = 0; k < 64; ++k) {
      acc0 += a[k] * wl0[k] + xr[k] * wr0[k];
      acc1 += a[k] * wl1[k] + xr[k] * wr1[k];
    }
    sO[lane][j]     = __float2bfloat16(fmaxf(acc0, 0.f));
    sO[lane][j + 1] = __float2bfloat16(fmaxf(acc1, 0.f));
  }
  __syncthreads();
  // 64 rows x 128 bf16 = 64 u32/row; 4096 u32 / 256 thr = 16 iters, coalesced.
#pragma unroll
  for (int it = 0; it < 16; ++it) {
    int idx = it * 256 + threadIdx.x;
    int r = idx >> 6, c = idx & 63;
    int nn = n0 + r;
    if (nn < n)
      *(uint32_t*)((char*)(h + (size_t)nn * 128) + c * 4) =
          *(uint32_t*)((char*)&sO[r][0] + c * 4);
  }
}

// y2 = h@Wl2 (128->64). lane = node, wave owns 16 of 64 outputs.
__global__ __launch_bounds__(256) void k_gemm2(const __hip_bfloat16* __restrict__ h,
                                               const float* __restrict__ WT,
                                               __hip_bfloat16* __restrict__ y2, int n) {
  __shared__ __align__(16) __hip_bfloat16 sO[64][66];
  const int lane = threadIdx.x & 63;
  const int w = __builtin_amdgcn_readfirstlane((int)(threadIdx.x >> 6));
  const int n0 = blockIdx.x * 64;
  const int node = (n0 + lane < n) ? (n0 + lane) : (n - 1);

  float a[128];
  const uint4* p = (const uint4*)(h + (size_t)node * 128);
#pragma unroll
  for (int c = 0; c < 16; ++c) unpack8(p[c], &a[c * 8]);

  const int j0 = w * 16;
  for (int jj = 0; jj < 16; jj += 2) {
    int j = j0 + jj;
    const float* w0 = WT + j * 128;
    const float* w1 = WT + (j + 1) * 128;
    float acc0 = 0.f, acc1 = 0.f;
#pragma unroll
    for (int k = 0; k < 128; ++k) { acc0 += a[k] * w0[k]; acc1 += a[k] * w1[k]; }
    sO[lane][j]     = __float2bfloat16(acc0);
    sO[lane][j + 1] = __float2bfloat16(acc1);
  }
  __syncthreads();
  // 64 rows x 64 bf16 = 32 u32/row; 2048 u32 / 256 thr = 8 iters.
#pragma unroll
  for (int it = 0; it < 8; ++it) {
    int idx = it * 256 + threadIdx.x;
    int r = idx >> 5, c = idx & 31;
    int nn = n0 + r;
    if (nn < n)
      *(uint32_t*)((char*)(y2 + (size_t)nn * 64) + c * 4) =
          *(uint32_t*)((char*)&sO[r][0] + c * 4);
  }
}

// out = sigmoid(agg2 + h@Wr2 + b2). lane = node, wave owns 16 of 64 outputs.
__global__ __launch_bounds__(256) void k_final(const __hip_bfloat16* __restrict__ h,
                                               const __hip_bfloat16* __restrict__ agg2,
                                               const float* __restrict__ WT,
                                               const float* __restrict__ b2,
                                               float* __restrict__ out, int n) {
  __shared__ float sO[64][65];
  const int lane = threadIdx.x & 63;
  const int w = __builtin_amdgcn_readfirstlane((int)(threadIdx.x >> 6));
  const int n0 = blockIdx.x * 64;
  const int node = (n0 + lane < n) ? (n0 + lane) : (n - 1);

  float a[128];
  const uint4* p = (const uint4*)(h + (size_t)node * 128);
#pragma unroll
  for (int c = 0; c < 16; ++c) unpack8(p[c], &a[c * 8]);

  const int j0 = w * 16;
  for (int jj = 0; jj < 16; jj += 2) {
    int j = j0 + jj;
    const float* w0 = WT + j * 128;
    const float* w1 = WT + (j + 1) * 128;
    float acc0 = b2[j] + ldf(agg2 + (size_t)node * 64 + j);
    float acc1 = b2[j + 1] + ldf(agg2 + (size_t)node * 64 + j + 1);
#pragma unroll
    for (int k = 0; k < 128; ++k) { acc0 += a[k] * w0[k]; acc1 += a[k] * w1[k]; }
    sO[lane][j]     = 1.f / (1.f + __expf(-acc0));
    sO[lane][j + 1] = 1.f / (1.f + __expf(-acc1));
  }
  __syncthreads();
#pragma unroll
  for (int it = 0; it < 16; ++it) {
    int idx = it * 256 + threadIdx.x;
    int r = idx >> 6, c = idx & 63;
    int nn = n0 + r;
    if (nn < n) out[(size_t)nn * 64 + c] = sO[r][c];
  }
}

extern "C" void kernel_launch(void* const* d_in, const int* in_sizes, int n_in,
                              void* d_out, int out_size, void* d_ws, size_t ws_size,
                              hipStream_t stream) {
  const float* x   = (const float*)d_in[0];
  const int*   ei  = (const int*)d_in[1];
  const float* Wl1 = (const float*)d_in[2];
  const float* Wr1 = (const float*)d_in[3];
  const float* b1  = (const float*)d_in[4];
  const float* Wl2 = (const float*)d_in[5];
  const float* Wr2 = (const float*)d_in[6];
  const float* b2  = (const float*)d_in[7];
  float* out = (float*)d_out;

  const int N = in_sizes[0] / 64;
  const int E = in_sizes[1] / 2;
  const int* src = ei;
  const int* dst = ei + E;

  char* wp = (char*)d_ws;
  auto take = [&](size_t bytes) {
    char* p = wp;
    wp += (bytes + 255) & ~(size_t)255;
    return p;
  };
  int* deg    = (int*)take((size_t)(N + 1) * 4);
  int* rowptr = (int*)take((size_t)(N + 1) * 4);
  int* cursor = (int*)take((size_t)N * 4);
  int* csr    = (int*)take((size_t)E * 4);
  float* WlT  = (float*)take(64 * 128 * 4);
  float* WrT  = (float*)take(64 * 128 * 4);
  float* W2lT = (float*)take(128 * 64 * 4);
  float* W2rT = (float*)take(128 * 64 * 4);
  __hip_bfloat16* agg = (__hip_bfloat16*)take((size_t)N * 64 * 2);   // agg1, reused as agg2
  __hip_bfloat16* h   = (__hip_bfloat16*)take((size_t)N * 128 * 2);
  __hip_bfloat16* y2  = (__hip_bfloat16*)take((size_t)N * 64 * 2);

  hipMemsetAsync(deg, 0, (size_t)(N + 1) * 4, stream);

  const int eb = (E + 255) / 256;
  const int nb = (N + 63) / 64;

  k_hist<<<eb, 256, 0, stream>>>(dst, deg, E);
  k_scan<<<1, 1024, 0, stream>>>(deg, rowptr, cursor, N);
  k_fill<<<eb, 256, 0, stream>>>(src, dst, cursor, csr, E);
  k_transpose<<<32, 256, 0, stream>>>(Wl1, Wr1, Wl2, Wr2, WlT, WrT, W2lT, W2rT);

  k_agg<float><<<2048, 256, 0, stream>>>(x, rowptr, csr, agg, N);
  k_gemm1<<<nb, 256, 0, stream>>>(x, agg, WlT, WrT, b1, h, N);
  k_gemm2<<<nb, 256, 0, stream>>>(h, W2lT, y2, N);
  k_agg<__hip_bfloat16><<<2048, 256, 0, stream>>>(y2, rowptr, csr, agg, N);
  k_final<<<nb, 256, 0, stream>>>(h, agg, W2rT, b2, out, N);
}